// Round 1
// baseline (397.162 us; speedup 1.0000x reference)
//
#include <hip/hip_runtime.h>
#include <hip/hip_bf16.h>
#include <math.h>

// InfoNCE fused: prep (normalize->bf16) -> gram (MFMA + exp epilogue) -> finalize
#define N2     8192
#define HALF_N 4096
#define DD     512
#define BM     128
#define BN     128
#define BK     32
#define NKT    (DD / BK)   // 16 k-tiles
#define LDK    (BK + 8)    // 40 ushorts = 80 B row stride: multiple of 16 B, bank-optimal

typedef __attribute__((ext_vector_type(8))) short bf16x8;   // 8 bf16 in 4 VGPRs
typedef __attribute__((ext_vector_type(4))) float f32x4;

// ---------------- prep: row-normalize z1|z2, emit bf16 U, zero rowsum/out ----
__global__ __launch_bounds__(256) void prep_kernel(
    const float* __restrict__ z1, const float* __restrict__ z2,
    ushort* __restrict__ U, float* __restrict__ rowsum, float* __restrict__ out)
{
    const int tid = threadIdx.x;
    const int gt  = blockIdx.x * 256 + tid;
    if (gt < N2) rowsum[gt] = 0.0f;     // ws is re-poisoned 0xAA each call
    if (gt == 0) out[0]     = 0.0f;     // so is d_out

    const int wave = tid >> 6;
    const int lane = tid & 63;
    const int row  = blockIdx.x * 4 + wave;

    const float* src = (row < HALF_N) ? (z1 + (size_t)row * DD)
                                      : (z2 + (size_t)(row - HALF_N) * DD);
    float4 a = ((const float4*)src)[lane * 2 + 0];
    float4 b = ((const float4*)src)[lane * 2 + 1];
    float ss = a.x*a.x + a.y*a.y + a.z*a.z + a.w*a.w
             + b.x*b.x + b.y*b.y + b.z*b.z + b.w*b.w;
#pragma unroll
    for (int off = 32; off > 0; off >>= 1) ss += __shfl_xor(ss, off);
    const float inv = 1.0f / fmaxf(sqrtf(ss), 1e-8f);

    float v[8] = {a.x, a.y, a.z, a.w, b.x, b.y, b.z, b.w};
    union { ushort us[8]; uint4 q; } pk;
#pragma unroll
    for (int j = 0; j < 8; ++j) {
        union { float f; unsigned int u; } c; c.f = v[j] * inv;
        unsigned int u = c.u + 0x7fffu + ((c.u >> 16) & 1u);  // RNE f32->bf16
        pk.us[j] = (ushort)(u >> 16);
    }
    *((uint4*)(U + (size_t)row * DD + lane * 8)) = pk.q;
}

// ---------------- gram: S = U U^T tile, epilogue sum_j exp(10*S_ij), j != i ----
__global__ __launch_bounds__(256) void gram_kernel(
    const ushort* __restrict__ U, float* __restrict__ rowsum)
{
    __shared__ ushort Ash[2][BM][LDK];   // 2*128*40*2 = 20 KB
    __shared__ ushort Bsh[2][BN][LDK];   // 20 KB  -> 40 KB total

    const int tid  = threadIdx.x;
    const int bx   = blockIdx.x & 63;    // col block (N2/BN = 64)
    const int by   = blockIdx.x >> 6;    // row block
    const int wave = tid >> 6;
    const int lane = tid & 63;
    const int wr   = wave >> 1;          // wave's 64-row half
    const int wc   = wave & 1;           // wave's 64-col half

    const size_t arow0 = (size_t)by * BM;
    const size_t brow0 = (size_t)bx * BN;

    // staging map: 64 lanes*16B = 16 rows x 64B ; 256 threads = 64 rows/pass, 2 passes
    const int lrow = tid >> 2;           // 0..63
    const int lseg = tid & 3;            // 0..3 (16 B segments)

    f32x4 acc[4][4];
#pragma unroll
    for (int i = 0; i < 4; ++i)
#pragma unroll
        for (int j = 0; j < 4; ++j) acc[i][j] = (f32x4){0.f, 0.f, 0.f, 0.f};

    uint4 ra[2], rb[2];
    auto gload = [&](int kt) {
#pragma unroll
        for (int p = 0; p < 2; ++p) {
            const int r = p * 64 + lrow;
            ra[p] = *((const uint4*)(U + (arow0 + r) * DD + kt * BK + lseg * 8));
            rb[p] = *((const uint4*)(U + (brow0 + r) * DD + kt * BK + lseg * 8));
        }
    };
    auto sstore = [&](int buf) {
#pragma unroll
        for (int p = 0; p < 2; ++p) {
            const int r = p * 64 + lrow;
            *((uint4*)&Ash[buf][r][lseg * 8]) = ra[p];
            *((uint4*)&Bsh[buf][r][lseg * 8]) = rb[p];
        }
    };

    gload(0);
    sstore(0);
    __syncthreads();

    for (int kt = 0; kt < NKT; ++kt) {
        const int buf = kt & 1;
        if (kt + 1 < NKT) gload(kt + 1);   // prefetch into regs (vmcnt pending)

        // fragment reads: A[m=lane&15][k=quad*8+j], B mirrors A (Gram => same gather)
        const int fr = lane & 15;
        const int fk = (lane >> 4) * 8;
        bf16x8 af[4], bfr[4];
#pragma unroll
        for (int t = 0; t < 4; ++t) {
            af[t]  = *((const bf16x8*)&Ash[buf][wr * 64 + t * 16 + fr][fk]);
            bfr[t] = *((const bf16x8*)&Bsh[buf][wc * 64 + t * 16 + fr][fk]);
        }
#pragma unroll
        for (int ct = 0; ct < 4; ++ct)
#pragma unroll
            for (int rt = 0; rt < 4; ++rt)
                acc[rt][ct] = __builtin_amdgcn_mfma_f32_16x16x32_bf16(
                                  af[rt], bfr[ct], acc[rt][ct], 0, 0, 0);

        if (kt + 1 < NKT) {
            sstore((kt + 1) & 1);          // waits the prefetch, writes other buffer
            __syncthreads();
        }
    }

    // epilogue: C/D layout col=lane&15, row=quad*4+reg ; exp2(s*10*log2e), skip diag
    const float SC   = 14.42695040888963f;   // 10 / ln(2)
    const int   quad = lane >> 4;
    const int   colv = (int)brow0 + wc * 64 + (lane & 15);
#pragma unroll
    for (int rt = 0; rt < 4; ++rt) {
        const int rowb = (int)arow0 + wr * 64 + rt * 16 + quad * 4;
#pragma unroll
        for (int reg = 0; reg < 4; ++reg) {
            const int grow = rowb + reg;
            float s = 0.f;
#pragma unroll
            for (int ct = 0; ct < 4; ++ct) {
                const int gcol = colv + ct * 16;
                const float e  = exp2f(acc[rt][ct][reg] * SC);
                s += (gcol == grow) ? 0.f : e;
            }
            s += __shfl_xor(s, 1);
            s += __shfl_xor(s, 2);
            s += __shfl_xor(s, 4);
            s += __shfl_xor(s, 8);
            if ((lane & 15) == 0) atomicAdd(&rowsum[grow], s);
        }
    }
}

// ---------------- finalize: nll_i = -10*dot(u_i,u_pos) + ln(rowsum_i); mean ----
__global__ __launch_bounds__(256) void finalize_kernel(
    const ushort* __restrict__ U, const float* __restrict__ rowsum,
    float* __restrict__ out)
{
    const int tid  = threadIdx.x;
    const int wave = tid >> 6;
    const int lane = tid & 63;
    const int row  = blockIdx.x * 4 + wave;
    const int prow = (row + HALF_N) & (N2 - 1);

    union { uint4 q; ushort s[8]; } xa, ya;
    xa.q = *((const uint4*)(U + (size_t)row  * DD + lane * 8));
    ya.q = *((const uint4*)(U + (size_t)prow * DD + lane * 8));
    float dot = 0.f;
#pragma unroll
    for (int j = 0; j < 8; ++j) {
        const float x = __uint_as_float((unsigned int)xa.s[j] << 16);
        const float y = __uint_as_float((unsigned int)ya.s[j] << 16);
        dot += x * y;
    }
#pragma unroll
    for (int off = 32; off > 0; off >>= 1) dot += __shfl_xor(dot, off);

    __shared__ float part[4];
    if (lane == 0) part[wave] = -10.0f * dot + logf(rowsum[row]);
    __syncthreads();
    if (tid == 0)
        atomicAdd(out, (part[0] + part[1] + part[2] + part[3]) * (1.0f / N2));
}

extern "C" void kernel_launch(void* const* d_in, const int* in_sizes, int n_in,
                              void* d_out, int out_size, void* d_ws, size_t ws_size,
                              hipStream_t stream)
{
    const float* z1 = (const float*)d_in[0];
    const float* z2 = (const float*)d_in[1];
    float* out      = (float*)d_out;
    ushort* U       = (ushort*)d_ws;                                  // 8 MB bf16 units
    float*  rowsum  = (float*)((char*)d_ws + (size_t)N2 * DD * 2);    // 32 KB

    prep_kernel<<<N2 / 4, 256, 0, stream>>>(z1, z2, U, rowsum, out);
    gram_kernel<<<(N2 / BM) * (N2 / BN), 256, 0, stream>>>(U, rowsum);
    finalize_kernel<<<N2 / 4, 256, 0, stream>>>(U, rowsum, out);
}

// Round 2
// 149.830 us; speedup vs baseline: 2.6507x; 2.6507x over previous
//
#include <hip/hip_runtime.h>
#include <hip/hip_bf16.h>
#include <math.h>

// InfoNCE fused, symmetric-Gram version:
//   prep     : row-normalize z1|z2 -> bf16 U (8 MB ws)
//   gram     : upper-tri 128x128 MFMA tiles, exp epilogue -> partials[j][i] (store-once, no atomics)
//   finalize : nll_i = -10*dot(u_i,u_pos) + ln(sum_j partials[j][i]); mean
#define N2     8192
#define HALF_N 4096
#define DD     512
#define BM     128
#define BN     128
#define BK     32
#define NKT    (DD / BK)          // 16 k-tiles
#define NB     (N2 / BM)          // 64 block-rows/cols
#define NTRI   (NB * (NB + 1) / 2) // 2080 upper-tri blocks

typedef __attribute__((ext_vector_type(8))) short bf16x8;   // 8 bf16 (4 VGPRs)
typedef __attribute__((ext_vector_type(4))) float f32x4;

__device__ __forceinline__ void load16_lds(const void* g, void* l) {
    // async global->LDS DMA, 16 B/lane; LDS dest = wave-uniform base + lane*16
    __builtin_amdgcn_global_load_lds(
        (const __attribute__((address_space(1))) void*)g,
        (__attribute__((address_space(3))) void*)l, 16, 0, 0);
}

// ---------------- prep: normalize rows, emit bf16, zero out ----------------
__global__ __launch_bounds__(256) void prep_kernel(
    const float* __restrict__ z1, const float* __restrict__ z2,
    ushort* __restrict__ U, float* __restrict__ out)
{
    const int tid = threadIdx.x;
    if (blockIdx.x == 0 && tid == 0) out[0] = 0.0f;   // d_out re-poisoned each call

    const int wave = tid >> 6;
    const int lane = tid & 63;
    const int row  = blockIdx.x * 4 + wave;

    const float* src = (row < HALF_N) ? (z1 + (size_t)row * DD)
                                      : (z2 + (size_t)(row - HALF_N) * DD);
    float4 a = ((const float4*)src)[lane * 2 + 0];
    float4 b = ((const float4*)src)[lane * 2 + 1];
    float ss = a.x*a.x + a.y*a.y + a.z*a.z + a.w*a.w
             + b.x*b.x + b.y*b.y + b.z*b.z + b.w*b.w;
#pragma unroll
    for (int off = 32; off > 0; off >>= 1) ss += __shfl_xor(ss, off);
    const float inv = 1.0f / fmaxf(sqrtf(ss), 1e-8f);

    float v[8] = {a.x, a.y, a.z, a.w, b.x, b.y, b.z, b.w};
    union { ushort us[8]; uint4 q; } pk;
#pragma unroll
    for (int j = 0; j < 8; ++j) {
        union { float f; unsigned int u; } c; c.f = v[j] * inv;
        unsigned int u = c.u + 0x7fffu + ((c.u >> 16) & 1u);  // RNE f32->bf16
        pk.us[j] = (ushort)(u >> 16);
    }
    *((uint4*)(U + (size_t)row * DD + lane * 8)) = pk.q;
}

// ---------------- gram: upper-tri tiles, S = U U^T, exp-sum epilogue -------
// LDS layout per tile row (64 B = 4 x 16B segs): seg s stored at slot s ^ ((row>>1)&3)
// -> ds_read_b128 frag reads are exactly 2-way bank-aliased (free), DMA dest contiguous.
__global__ __launch_bounds__(256) void gram_kernel(
    const ushort* __restrict__ U, float* __restrict__ partials)
{
    __shared__ ushort Ash[2][BM][BK];   // 2*8 KB
    __shared__ ushort Bsh[2][BN][BK];   // 2*8 KB  -> 32 KB
    __shared__ float rowacc[BM];
    __shared__ float colacc[BN];

    const int tid  = threadIdx.x;
    const int wave = tid >> 6;
    const int lane = tid & 63;

    // linear block id -> (by, bx), by <= bx ; t0(by) = by*(129-by)/2
    const int t = blockIdx.x;
    int by = (int)((129.0 - sqrt(16641.0 - 8.0 * (double)t)) * 0.5);
    by = min(max(by, 0), NB - 1);
    while (by > 0       && t <  (by * (129 - by)) / 2) --by;
    while (by < NB - 1  && t >= ((by + 1) * (128 - by)) / 2) ++by;
    const int bx = by + (t - (by * (129 - by)) / 2);

    const int wr = wave >> 1;            // row half (0/1)
    const int wc = wave & 1;             // col half (0/1)
    const size_t arow0 = (size_t)by * BM;
    const size_t brow0 = (size_t)bx * BN;

    if (tid < BM) rowacc[tid] = 0.f;
    else          colacc[tid - BM] = 0.f;

    // staging: chunk = 16 rows x 64 B = 1024 B = one wave-DMA; 8 chunks/tile, 2 per wave
    const int sseg = (lane & 3) ^ ((lane >> 3) & 3);   // source seg for swizzled slot

    auto stage = [&](int kt, int buf) {
        const int k0 = kt * BK;
#pragma unroll
        for (int h = 0; h < 2; ++h) {
            const int c = wave * 2 + h;              // chunk 0..7
            const int r = c * 16 + (lane >> 2);
            load16_lds(U + (arow0 + r) * DD + k0 + sseg * 8, &Ash[buf][c * 16][0]);
            load16_lds(U + (brow0 + r) * DD + k0 + sseg * 8, &Bsh[buf][c * 16][0]);
        }
    };

    f32x4 acc[4][4];
#pragma unroll
    for (int i = 0; i < 4; ++i)
#pragma unroll
        for (int j = 0; j < 4; ++j) acc[i][j] = (f32x4){0.f, 0.f, 0.f, 0.f};

    const int fr   = lane & 15;
    const int quad = lane >> 4;
    const int slot = (quad ^ ((fr >> 1) & 3)) * 8;   // element offset of swizzled seg

    stage(0, 0);
    __syncthreads();

    for (int kt = 0; kt < NKT; ++kt) {
        const int buf = kt & 1;
        if (kt + 1 < NKT) stage(kt + 1, buf ^ 1);    // async, drained by barrier below

        bf16x8 af[4], bfr[4];
#pragma unroll
        for (int tt = 0; tt < 4; ++tt) {
            af[tt]  = *(const bf16x8*)&Ash[buf][wr * 64 + tt * 16 + fr][slot];
            bfr[tt] = *(const bf16x8*)&Bsh[buf][wc * 64 + tt * 16 + fr][slot];
        }
#pragma unroll
        for (int ct = 0; ct < 4; ++ct)
#pragma unroll
            for (int rt = 0; rt < 4; ++rt)
                acc[rt][ct] = __builtin_amdgcn_mfma_f32_16x16x32_bf16(
                                  af[rt], bfr[ct], acc[rt][ct], 0, 0, 0);
        __syncthreads();
    }

    // epilogue: C/D layout col=lane&15, row=quad*4+reg
    // row sums (mask diag) + col sums (off-diag blocks contribute to rowsum[col])
    const float SC = 14.42695040888963f;   // 10 / ln(2)
    float cacc[4] = {0.f, 0.f, 0.f, 0.f};
#pragma unroll
    for (int rt = 0; rt < 4; ++rt) {
        const int lrow = wr * 64 + rt * 16 + quad * 4;
#pragma unroll
        for (int reg = 0; reg < 4; ++reg) {
            const int grow = (int)arow0 + lrow + reg;
            float s = 0.f;
#pragma unroll
            for (int ct = 0; ct < 4; ++ct) {
                const int gcol = (int)brow0 + wc * 64 + ct * 16 + fr;
                const float e  = exp2f(acc[rt][ct][reg] * SC);
                s += (gcol == grow) ? 0.f : e;      // diag only possible when by==bx
                cacc[ct] += e;
            }
            s += __shfl_xor(s, 1);
            s += __shfl_xor(s, 2);
            s += __shfl_xor(s, 4);
            s += __shfl_xor(s, 8);
            if (fr == 0) atomicAdd(&rowacc[lrow + reg], s);   // LDS atomic (ds_add_f32)
        }
    }
    if (by != bx) {
#pragma unroll
        for (int ct = 0; ct < 4; ++ct) {
            float c = cacc[ct];
            c += __shfl_xor(c, 16);
            c += __shfl_xor(c, 32);
            if (quad == 0) atomicAdd(&colacc[wc * 64 + ct * 16 + fr], c);
        }
    }
    __syncthreads();

    // store-once partials: partials[j][i] = contribution of col-block j to rowsum[i]
    if (tid < BM) {
        partials[(size_t)bx * N2 + arow0 + tid] = rowacc[tid];
        if (by != bx)
            partials[(size_t)by * N2 + brow0 + tid] = colacc[tid];
    }
}

// ---------------- finalize: nll_i = -10*dot + ln(sum_j partials[j][i]) -----
__global__ __launch_bounds__(256) void finalize_kernel(
    const ushort* __restrict__ U, const float* __restrict__ partials,
    float* __restrict__ out)
{
    const int tid  = threadIdx.x;
    const int wave = tid >> 6;
    const int lane = tid & 63;
    const int row  = blockIdx.x * 4 + wave;
    const int prow = (row + HALF_N) & (N2 - 1);

    union { uint4 q; ushort s[8]; } xa, ya;
    xa.q = *((const uint4*)(U + (size_t)row  * DD + lane * 8));
    ya.q = *((const uint4*)(U + (size_t)prow * DD + lane * 8));
    float dot = 0.f;
#pragma unroll
    for (int j = 0; j < 8; ++j) {
        const float x = __uint_as_float((unsigned int)xa.s[j] << 16);
        const float y = __uint_as_float((unsigned int)ya.s[j] << 16);
        dot += x * y;
    }
    float ps = partials[(size_t)lane * N2 + row];   // lane j = col-block j (64 of them)
#pragma unroll
    for (int off = 32; off > 0; off >>= 1) {
        dot += __shfl_xor(dot, off);
        ps  += __shfl_xor(ps,  off);
    }

    __shared__ float part[4];
    if (lane == 0) part[wave] = -10.0f * dot + logf(ps);
    __syncthreads();
    if (tid == 0)
        atomicAdd(out, (part[0] + part[1] + part[2] + part[3]) * (1.0f / N2));
}

extern "C" void kernel_launch(void* const* d_in, const int* in_sizes, int n_in,
                              void* d_out, int out_size, void* d_ws, size_t ws_size,
                              hipStream_t stream)
{
    const float* z1 = (const float*)d_in[0];
    const float* z2 = (const float*)d_in[1];
    float* out      = (float*)d_out;
    ushort* U       = (ushort*)d_ws;                                   // 8 MB bf16 units
    float*  partials= (float*)((char*)d_ws + (size_t)N2 * DD * 2);     // 64*8192*4 = 2 MB

    prep_kernel<<<N2 / 4, 256, 0, stream>>>(z1, z2, U, out);
    gram_kernel<<<NTRI, 256, 0, stream>>>(U, partials);
    finalize_kernel<<<N2 / 4, 256, 0, stream>>>(U, partials, out);
}

// Round 4
// 145.361 us; speedup vs baseline: 2.7322x; 1.0307x over previous
//
#include <hip/hip_runtime.h>
#include <hip/hip_bf16.h>
#include <math.h>

// InfoNCE fused, symmetric-Gram:
//   prep     : row-normalize z1|z2 -> bf16 U
//   gram     : upper-tri 128x128 MFMA tiles, exp epilogue -> partials[j][i] (store-once)
//              + pos-pair dots extracted from blocks with bx == by+32
//   finalize : nll_i = -10*posdot[i%4096] + ln(sum_j partials[j][i]); mean (32 atomics)
#define N2     8192
#define HALF_N 4096
#define DD     512
#define BM     128
#define BN     128
#define BK     32
#define NKT    (DD / BK)           // 16 k-tiles
#define NB     (N2 / BM)           // 64 block-rows/cols
#define NTRI   (NB * (NB + 1) / 2) // 2080 upper-tri blocks

#define U_BYTES    ((size_t)N2 * DD * 2)      // 8 MB
#define PART_BYTES ((size_t)NB * N2 * 4)      // 2 MB
#define PD_BYTES   ((size_t)HALF_N * 4)       // 16 KB

typedef __attribute__((ext_vector_type(8))) short bf16x8;   // 8 bf16 (4 VGPRs)
typedef __attribute__((ext_vector_type(4))) float f32x4;

__device__ __forceinline__ void load16_lds(const void* g, void* l) {
    // async global->LDS DMA, 16 B/lane; LDS dest = wave-uniform base + lane*16
    __builtin_amdgcn_global_load_lds(
        (const __attribute__((address_space(1))) void*)g,
        (__attribute__((address_space(3))) void*)l, 16, 0, 0);
}

// ---------------- prep: normalize rows, emit bf16, zero out ----------------
__global__ __launch_bounds__(256) void prep_kernel(
    const float* __restrict__ z1, const float* __restrict__ z2,
    ushort* __restrict__ U, float* __restrict__ out)
{
    const int tid = threadIdx.x;
    if (blockIdx.x == 0 && tid == 0) out[0] = 0.0f;   // d_out re-poisoned each call

    const int wave = tid >> 6;
    const int lane = tid & 63;
    const int row  = blockIdx.x * 4 + wave;

    const float* src = (row < HALF_N) ? (z1 + (size_t)row * DD)
                                      : (z2 + (size_t)(row - HALF_N) * DD);
    float4 a = ((const float4*)src)[lane * 2 + 0];
    float4 b = ((const float4*)src)[lane * 2 + 1];
    float ss = a.x*a.x + a.y*a.y + a.z*a.z + a.w*a.w
             + b.x*b.x + b.y*b.y + b.z*b.z + b.w*b.w;
#pragma unroll
    for (int off = 32; off > 0; off >>= 1) ss += __shfl_xor(ss, off);
    const float inv = 1.0f / fmaxf(sqrtf(ss), 1e-8f);

    float v[8] = {a.x, a.y, a.z, a.w, b.x, b.y, b.z, b.w};
    union { ushort us[8]; uint4 q; } pk;
#pragma unroll
    for (int j = 0; j < 8; ++j) {
        union { float f; unsigned int u; } c; c.f = v[j] * inv;
        unsigned int u = c.u + 0x7fffu + ((c.u >> 16) & 1u);  // RNE f32->bf16
        pk.us[j] = (ushort)(u >> 16);
    }
    *((uint4*)(U + (size_t)row * DD + lane * 8)) = pk.q;
}

// ---------------- gram: upper-tri tiles, S = U U^T, exp-sum epilogue -------
// LDS row = 64 B = 4 x 16B segs; seg s lives at slot s ^ ((row>>1)&3)
// -> ds_read_b128 frag reads are exactly 2-way bank-aliased (free), DMA dest contiguous.
__global__ __launch_bounds__(256) void gram_kernel(
    const ushort* __restrict__ U, float* __restrict__ partials,
    float* __restrict__ posdot)
{
    __shared__ ushort Ash[2][BM][BK];   // 16 KB
    __shared__ ushort Bsh[2][BN][BK];   // 16 KB
    __shared__ float racc[2][BM];       // [wc][row]  (split -> no LDS atomics)
    __shared__ float cacc[2][BN];       // [wr][col]

    const int tid  = threadIdx.x;
    const int wave = tid >> 6;
    const int lane = tid & 63;

    // linear block id -> (by, bx), by <= bx ; t0(by) = by*(129-by)/2
    const int t = blockIdx.x;
    int by = (int)((129.0 - sqrt(16641.0 - 8.0 * (double)t)) * 0.5);
    by = min(max(by, 0), NB - 1);
    while (by > 0       && t <  (by * (129 - by)) / 2) --by;
    while (by < NB - 1  && t >= ((by + 1) * (128 - by)) / 2) ++by;
    const int bx = by + (t - (by * (129 - by)) / 2);

    const int wr = wave >> 1;            // row half (0/1)
    const int wc = wave & 1;             // col half (0/1)
    const size_t arow0 = (size_t)by * BM;
    const size_t brow0 = (size_t)bx * BN;

    ((float*)racc)[tid] = 0.f;
    ((float*)cacc)[tid] = 0.f;

    // staging: chunk = 16 rows x 64 B = one wave-DMA; 8 chunks/tile, 2 per wave
    const int sseg = (lane & 3) ^ ((lane >> 3) & 3);   // source seg for swizzled slot

    auto stage = [&](int kt, int buf) {
        const int k0 = kt * BK;
#pragma unroll
        for (int h = 0; h < 2; ++h) {
            const int c = wave * 2 + h;              // chunk 0..7
            const int r = c * 16 + (lane >> 2);
            load16_lds(U + (arow0 + r) * DD + k0 + sseg * 8, &Ash[buf][c * 16][0]);
            load16_lds(U + (brow0 + r) * DD + k0 + sseg * 8, &Bsh[buf][c * 16][0]);
        }
    };

    f32x4 acc[4][4];
#pragma unroll
    for (int i = 0; i < 4; ++i)
#pragma unroll
        for (int j = 0; j < 4; ++j) acc[i][j] = (f32x4){0.f, 0.f, 0.f, 0.f};

    const int fr   = lane & 15;
    const int quad = lane >> 4;
    const int slot = (quad ^ ((fr >> 1) & 3)) * 8;   // element offset of swizzled seg

    stage(0, 0);
    __syncthreads();

    for (int kt = 0; kt < NKT; ++kt) {
        const int buf = kt & 1;
        if (kt + 1 < NKT) stage(kt + 1, buf ^ 1);    // async, drained by barrier below

        bf16x8 af[4], bfr[4];
#pragma unroll
        for (int tt = 0; tt < 4; ++tt) {
            af[tt]  = *(const bf16x8*)&Ash[buf][wr * 64 + tt * 16 + fr][slot];
            bfr[tt] = *(const bf16x8*)&Bsh[buf][wc * 64 + tt * 16 + fr][slot];
        }
#pragma unroll
        for (int ct = 0; ct < 4; ++ct)
#pragma unroll
            for (int rt = 0; rt < 4; ++rt)
                acc[rt][ct] = __builtin_amdgcn_mfma_f32_16x16x32_bf16(
                                  af[rt], bfr[ct], acc[rt][ct], 0, 0, 0);
        __syncthreads();
    }

    // epilogue: C/D layout col=lane&15, row=quad*4+reg
    const float SC = 14.42695040888963f;   // 10 / ln(2)
    if (by == bx) {
        // diagonal block: mask diag, row sums only (col path would double count)
#pragma unroll
        for (int rt = 0; rt < 4; ++rt) {
            const int lrow = wr * 64 + rt * 16 + quad * 4;
#pragma unroll
            for (int reg = 0; reg < 4; ++reg) {
                const int lr = lrow + reg;
                float s = 0.f;
#pragma unroll
                for (int ct = 0; ct < 4; ++ct) {
                    const int lc = wc * 64 + ct * 16 + fr;
                    const float e = exp2f(acc[rt][ct][reg] * SC);
                    s += (lc == lr) ? 0.f : e;
                }
                s += __shfl_xor(s, 1);
                s += __shfl_xor(s, 2);
                s += __shfl_xor(s, 4);
                s += __shfl_xor(s, 8);
                if (fr == 0) racc[wc][lr] = s;       // unique (wc,row) writer
            }
        }
    } else {
        float csum[4] = {0.f, 0.f, 0.f, 0.f};
#pragma unroll
        for (int rt = 0; rt < 4; ++rt) {
            const int lrow = wr * 64 + rt * 16 + quad * 4;
#pragma unroll
            for (int reg = 0; reg < 4; ++reg) {
                float s = 0.f;
#pragma unroll
                for (int ct = 0; ct < 4; ++ct) {
                    const float e = exp2f(acc[rt][ct][reg] * SC);
                    s += e;
                    csum[ct] += e;
                }
                s += __shfl_xor(s, 1);
                s += __shfl_xor(s, 2);
                s += __shfl_xor(s, 4);
                s += __shfl_xor(s, 8);
                if (fr == 0) racc[wc][lrow + reg] = s;
            }
        }
#pragma unroll
        for (int ct = 0; ct < 4; ++ct) {
            float c = csum[ct];
            c += __shfl_xor(c, 16);
            c += __shfl_xor(c, 32);
            if (quad == 0) cacc[wr][wc * 64 + ct * 16 + fr] = c;  // unique (wr,col)
        }
        // pos-pair dots: rows i, cols i+4096 -> local diagonal of (by, by+32) blocks
        if (posdot != nullptr && bx == by + 32 && wr == wc && quad == (fr >> 2)) {
#pragma unroll
            for (int rt = 0; rt < 4; ++rt)
                posdot[arow0 + wr * 64 + rt * 16 + fr] = acc[rt][rt][fr & 3];
        }
    }
    __syncthreads();

    // store-once partials: partials[j][i] = contribution of col-block j to rowsum[i]
    if (tid < BM) {
        partials[(size_t)bx * N2 + arow0 + tid] = racc[0][tid] + racc[1][tid];
        if (by != bx)
            partials[(size_t)by * N2 + brow0 + tid] = cacc[0][tid] + cacc[1][tid];
    }
}

// ---------------- finalize (fast): thread-per-row, 32 block atomics --------
__global__ __launch_bounds__(256) void finalize_fast(
    const float* __restrict__ partials, const float* __restrict__ posdot,
    float* __restrict__ out)
{
    const int tid = threadIdx.x;
    const int row = blockIdx.x * 256 + tid;
    float s = 0.f;
#pragma unroll 8
    for (int j = 0; j < NB; ++j) s += partials[(size_t)j * N2 + row];  // coalesced
    float nll = -10.0f * posdot[row & (HALF_N - 1)] + logf(s);
#pragma unroll
    for (int off = 32; off > 0; off >>= 1) nll += __shfl_xor(nll, off);
    __shared__ float red[4];
    if ((tid & 63) == 0) red[tid >> 6] = nll;
    __syncthreads();
    if (tid == 0)
        atomicAdd(out, (red[0] + red[1] + red[2] + red[3]) * (1.0f / N2));
}

// ---------------- finalize (fallback, if ws too small for posdot) ---------
__global__ __launch_bounds__(256) void finalize_slow(
    const ushort* __restrict__ U, const float* __restrict__ partials,
    float* __restrict__ out)
{
    const int tid  = threadIdx.x;
    const int wave = tid >> 6;
    const int lane = tid & 63;
    const int row  = blockIdx.x * 4 + wave;
    const int prow = (row + HALF_N) & (N2 - 1);

    union { uint4 q; ushort s[8]; } xa, ya;
    xa.q = *((const uint4*)(U + (size_t)row  * DD + lane * 8));
    ya.q = *((const uint4*)(U + (size_t)prow * DD + lane * 8));
    float dot = 0.f;
#pragma unroll
    for (int j = 0; j < 8; ++j) {
        const float x = __uint_as_float((unsigned int)xa.s[j] << 16);
        const float y = __uint_as_float((unsigned int)ya.s[j] << 16);
        dot += x * y;
    }
    float ps = partials[(size_t)lane * N2 + row];
#pragma unroll
    for (int off = 32; off > 0; off >>= 1) {
        dot += __shfl_xor(dot, off);
        ps  += __shfl_xor(ps,  off);
    }
    __shared__ float part[4];
    if (lane == 0) part[wave] = -10.0f * dot + logf(ps);
    __syncthreads();
    if (tid == 0)
        atomicAdd(out, (part[0] + part[1] + part[2] + part[3]) * (1.0f / N2));
}

extern "C" void kernel_launch(void* const* d_in, const int* in_sizes, int n_in,
                              void* d_out, int out_size, void* d_ws, size_t ws_size,
                              hipStream_t stream)
{
    const float* z1 = (const float*)d_in[0];
    const float* z2 = (const float*)d_in[1];
    float* out      = (float*)d_out;
    ushort* U        = (ushort*)d_ws;
    float*  partials = (float*)((char*)d_ws + U_BYTES);
    float*  posdot   = (float*)((char*)d_ws + U_BYTES + PART_BYTES);
    const bool has_pd = ws_size >= U_BYTES + PART_BYTES + PD_BYTES;

    prep_kernel<<<N2 / 4, 256, 0, stream>>>(z1, z2, U, out);
    gram_kernel<<<NTRI, 256, 0, stream>>>(U, partials, has_pd ? posdot : nullptr);
    if (has_pd)
        finalize_fast<<<N2 / 256, 256, 0, stream>>>(partials, posdot, out);
    else
        finalize_slow<<<N2 / 4, 256, 0, stream>>>(U, partials, out);
}

// Round 5
// 107.585 us; speedup vs baseline: 3.6916x; 1.3511x over previous
//
#include <hip/hip_runtime.h>
#include <hip/hip_bf16.h>
#include <math.h>

// InfoNCE fused, symmetric-Gram, fp8-e4m3 Gram MFMA:
//   prep     : row-normalize z1|z2 -> fp8 U (4 MB), k-permuted per 64B group
//   gram     : upper-tri 128x128 tiles, mfma_f32_16x16x32_fp8_fp8, exp epilogue
//              -> partials[j][i] (store-once) + pos-pair dots (bx == by+32 diagonals)
//   finalize : nll_i = -10*posdot[i%4096] + ln(sum_j partials[j][i]); mean (32 atomics)
#define N2     8192
#define HALF_N 4096
#define DD     512
#define BM     128
#define BN     128
#define BKB    64                  // K-bytes per tile = K=64 fp8
#define NKT    (DD / BKB)          // 8 k-tiles
#define NB     (N2 / BM)           // 64 block-rows/cols
#define NTRI   (NB * (NB + 1) / 2) // 2080 upper-tri blocks

#define U_BYTES    ((size_t)N2 * DD)          // 4 MB (fp8)
#define PART_BYTES ((size_t)NB * N2 * 4)      // 2 MB
#define PD_BYTES   ((size_t)HALF_N * 4)       // 16 KB

typedef __attribute__((ext_vector_type(4))) float f32x4;
typedef __attribute__((ext_vector_type(2))) long  l64x2;   // 16 B = two fp8 K=32 frags

__device__ __forceinline__ void load16_lds(const void* g, void* l) {
    // async global->LDS DMA, 16 B/lane; LDS dest = wave-uniform base + lane*16
    __builtin_amdgcn_global_load_lds(
        (const __attribute__((address_space(1))) void*)g,
        (__attribute__((address_space(3))) void*)l, 16, 0, 0);
}

// ---------------- prep: normalize rows, emit k-permuted fp8, zero out ------
// storage pos (per 64B group) = q*16 + h*8 + j  <->  logical k = q*8 + h*32 + j
// so a 16B LDS read at q*16 yields k=q*8..+7 (low 8B) and k=32+q*8..+7 (high 8B).
__global__ __launch_bounds__(256) void prep_kernel(
    const float* __restrict__ z1, const float* __restrict__ z2,
    unsigned char* __restrict__ U, float* __restrict__ out)
{
    const int tid = threadIdx.x;
    if (blockIdx.x == 0 && tid == 0) out[0] = 0.0f;   // d_out re-poisoned each call

    const int wave = tid >> 6;
    const int lane = tid & 63;
    const int row  = blockIdx.x * 4 + wave;

    const float* src = (row < HALF_N) ? (z1 + (size_t)row * DD)
                                      : (z2 + (size_t)(row - HALF_N) * DD);
    float4 a = ((const float4*)src)[lane * 2 + 0];
    float4 b = ((const float4*)src)[lane * 2 + 1];
    float ss = a.x*a.x + a.y*a.y + a.z*a.z + a.w*a.w
             + b.x*b.x + b.y*b.y + b.z*b.z + b.w*b.w;
#pragma unroll
    for (int off = 32; off > 0; off >>= 1) ss += __shfl_xor(ss, off);
    const float inv = 1.0f / fmaxf(sqrtf(ss), 1e-8f);

    int lo = __builtin_amdgcn_cvt_pk_fp8_f32(a.x * inv, a.y * inv, 0,  0);
    lo     = __builtin_amdgcn_cvt_pk_fp8_f32(a.z * inv, a.w * inv, lo, 1);
    int hi = __builtin_amdgcn_cvt_pk_fp8_f32(b.x * inv, b.y * inv, 0,  0);
    hi     = __builtin_amdgcn_cvt_pk_fp8_f32(b.z * inv, b.w * inv, hi, 1);

    const int g = lane >> 3;           // 64B group
    const int q = lane & 3;            // quad within group
    const int h = (lane >> 2) & 1;     // k-half within group
    *(int2*)(U + (size_t)row * DD + g * 64 + q * 16 + h * 8) = make_int2(lo, hi);
}

// ---------------- gram: upper-tri tiles, S = U U^T, exp-sum epilogue -------
// LDS row = 64 B = 4 x 16B segs; seg s lives at slot s ^ ((row>>1)&3)
// -> frag b128 reads exactly 2-way bank-aliased (free), DMA dest contiguous.
__global__ __launch_bounds__(256, 3) void gram_kernel(
    const unsigned char* __restrict__ U, float* __restrict__ partials,
    float* __restrict__ posdot)
{
    __shared__ unsigned char Ash[2][BM][BKB];   // 16 KB
    __shared__ unsigned char Bsh[2][BN][BKB];   // 16 KB
    __shared__ float racc[2][BM];               // [wc][row] (split -> no LDS atomics)
    __shared__ float cacc[2][BN];               // [wr][col]

    const int tid  = threadIdx.x;
    const int wave = tid >> 6;
    const int lane = tid & 63;

    // linear block id -> (by, bx), by <= bx ; t0(by) = by*(129-by)/2
    const int t = blockIdx.x;
    int by = (int)((129.0 - sqrt(16641.0 - 8.0 * (double)t)) * 0.5);
    by = min(max(by, 0), NB - 1);
    while (by > 0       && t <  (by * (129 - by)) / 2) --by;
    while (by < NB - 1  && t >= ((by + 1) * (128 - by)) / 2) ++by;
    const int bx = by + (t - (by * (129 - by)) / 2);

    const int wr = wave >> 1;            // row half (0/1)
    const int wc = wave & 1;             // col half (0/1)
    const size_t arow0 = (size_t)by * BM;
    const size_t brow0 = (size_t)bx * BN;

    ((float*)racc)[tid] = 0.f;
    ((float*)cacc)[tid] = 0.f;

    // staging: chunk = 16 rows x 64 B = one wave-DMA; 8 chunks/tile, 2 per wave
    const int sseg = (lane & 3) ^ ((lane >> 3) & 3);   // source seg for swizzled slot

    auto stage = [&](int kt, int buf) {
        const int k0 = kt * BKB;
#pragma unroll
        for (int hh = 0; hh < 2; ++hh) {
            const int c = wave * 2 + hh;             // chunk 0..7
            const int r = c * 16 + (lane >> 2);
            load16_lds(U + (arow0 + r) * DD + k0 + sseg * 16, &Ash[buf][c * 16][0]);
            load16_lds(U + (brow0 + r) * DD + k0 + sseg * 16, &Bsh[buf][c * 16][0]);
        }
    };

    f32x4 acc[4][4];
#pragma unroll
    for (int i = 0; i < 4; ++i)
#pragma unroll
        for (int j = 0; j < 4; ++j) acc[i][j] = (f32x4){0.f, 0.f, 0.f, 0.f};

    const int fr   = lane & 15;
    const int quad = lane >> 4;
    const int sb   = (quad ^ ((fr >> 1) & 3)) * 16;  // swizzled seg byte offset

    stage(0, 0);
    __syncthreads();

    for (int kt = 0; kt < NKT; ++kt) {
        const int buf = kt & 1;
        if (kt + 1 < NKT) stage(kt + 1, buf ^ 1);    // async, drained by barrier below

        l64x2 af[4], bfr[4];
#pragma unroll
        for (int tt = 0; tt < 4; ++tt) {
            af[tt]  = *(const l64x2*)&Ash[buf][wr * 64 + tt * 16 + fr][sb];
            bfr[tt] = *(const l64x2*)&Bsh[buf][wc * 64 + tt * 16 + fr][sb];
        }
#pragma unroll
        for (int ct = 0; ct < 4; ++ct)
#pragma unroll
            for (int rt = 0; rt < 4; ++rt) {
                acc[rt][ct] = __builtin_amdgcn_mfma_f32_16x16x32_fp8_fp8(
                                  af[rt].x, bfr[ct].x, acc[rt][ct], 0, 0, 0);
                acc[rt][ct] = __builtin_amdgcn_mfma_f32_16x16x32_fp8_fp8(
                                  af[rt].y, bfr[ct].y, acc[rt][ct], 0, 0, 0);
            }
        __syncthreads();
    }

    // epilogue: C/D layout col=lane&15, row=quad*4+reg (dtype-independent)
    const float SC = 14.42695040888963f;   // 10 / ln(2)
    if (by == bx) {
        // diagonal block: mask diag, row sums only (col path would double count)
#pragma unroll
        for (int rt = 0; rt < 4; ++rt) {
            const int lrow = wr * 64 + rt * 16 + quad * 4;
#pragma unroll
            for (int reg = 0; reg < 4; ++reg) {
                const int lr = lrow + reg;
                float s = 0.f;
#pragma unroll
                for (int ct = 0; ct < 4; ++ct) {
                    const int lc = wc * 64 + ct * 16 + fr;
                    const float e = exp2f(acc[rt][ct][reg] * SC);
                    s += (lc == lr) ? 0.f : e;
                }
                s += __shfl_xor(s, 1);
                s += __shfl_xor(s, 2);
                s += __shfl_xor(s, 4);
                s += __shfl_xor(s, 8);
                if (fr == 0) racc[wc][lr] = s;       // unique (wc,row) writer
            }
        }
    } else {
        float csum[4] = {0.f, 0.f, 0.f, 0.f};
#pragma unroll
        for (int rt = 0; rt < 4; ++rt) {
            const int lrow = wr * 64 + rt * 16 + quad * 4;
#pragma unroll
            for (int reg = 0; reg < 4; ++reg) {
                float s = 0.f;
#pragma unroll
                for (int ct = 0; ct < 4; ++ct) {
                    const float e = exp2f(acc[rt][ct][reg] * SC);
                    s += e;
                    csum[ct] += e;
                }
                s += __shfl_xor(s, 1);
                s += __shfl_xor(s, 2);
                s += __shfl_xor(s, 4);
                s += __shfl_xor(s, 8);
                if (fr == 0) racc[wc][lrow + reg] = s;
            }
        }
#pragma unroll
        for (int ct = 0; ct < 4; ++ct) {
            float c = csum[ct];
            c += __shfl_xor(c, 16);
            c += __shfl_xor(c, 32);
            if (quad == 0) cacc[wr][wc * 64 + ct * 16 + fr] = c;  // unique (wr,col)
        }
        // pos-pair dots: local diagonal of (by, by+32) blocks; static acc indexing
        if (posdot != nullptr && bx == by + 32 && wr == wc) {
#pragma unroll
            for (int rt = 0; rt < 4; ++rt) {
                const int lrow = rt * 16 + quad * 4;
#pragma unroll
                for (int reg = 0; reg < 4; ++reg)
                    if (fr == quad * 4 + reg)        // lane's col == its row
                        posdot[arow0 + wr * 64 + lrow + reg] = acc[rt][rt][reg];
            }
        }
    }
    __syncthreads();

    // store-once partials: partials[j][i] = contribution of col-block j to rowsum[i]
    if (tid < BM) {
        partials[(size_t)bx * N2 + arow0 + tid] = racc[0][tid] + racc[1][tid];
        if (by != bx)
            partials[(size_t)by * N2 + brow0 + tid] = cacc[0][tid] + cacc[1][tid];
    }
}

// ---------------- finalize (fast): thread-per-row, 32 block atomics --------
__global__ __launch_bounds__(256) void finalize_fast(
    const float* __restrict__ partials, const float* __restrict__ posdot,
    float* __restrict__ out)
{
    const int tid = threadIdx.x;
    const int row = blockIdx.x * 256 + tid;
    float s = 0.f;
#pragma unroll 8
    for (int j = 0; j < NB; ++j) s += partials[(size_t)j * N2 + row];  // coalesced
    float nll = -10.0f * posdot[row & (HALF_N - 1)] + logf(s);
#pragma unroll
    for (int off = 32; off > 0; off >>= 1) nll += __shfl_xor(nll, off);
    __shared__ float red[4];
    if ((tid & 63) == 0) red[tid >> 6] = nll;
    __syncthreads();
    if (tid == 0)
        atomicAdd(out, (red[0] + red[1] + red[2] + red[3]) * (1.0f / N2));
}

// ---------------- finalize (fallback, if ws too small for posdot) ---------
__device__ __forceinline__ float dec_e4m3(unsigned int b) {
    const int e = (b >> 3) & 15, m = b & 7;
    float v = e ? ldexpf((float)(8 + m), e - 10) : ldexpf((float)m, -9);
    return (b & 0x80u) ? -v : v;
}

__global__ __launch_bounds__(256) void finalize_slow(
    const unsigned char* __restrict__ U, const float* __restrict__ partials,
    float* __restrict__ out)
{
    const int tid  = threadIdx.x;
    const int wave = tid >> 6;
    const int lane = tid & 63;
    const int row  = blockIdx.x * 4 + wave;
    const int prow = (row + HALF_N) & (N2 - 1);

    // same k-permutation on both rows -> products pair correctly
    uint2 xa = *(const uint2*)(U + (size_t)row  * DD + lane * 8);
    uint2 ya = *(const uint2*)(U + (size_t)prow * DD + lane * 8);
    float dot = 0.f;
#pragma unroll
    for (int j = 0; j < 4; ++j)
        dot += dec_e4m3(xa.x >> (8 * j)) * dec_e4m3(ya.x >> (8 * j));
#pragma unroll
    for (int j = 0; j < 4; ++j)
        dot += dec_e4m3(xa.y >> (8 * j)) * dec_e4m3(ya.y >> (8 * j));

    float ps = partials[(size_t)lane * N2 + row];
#pragma unroll
    for (int off = 32; off > 0; off >>= 1) {
        dot += __shfl_xor(dot, off);
        ps  += __shfl_xor(ps,  off);
    }
    __shared__ float part[4];
    if (lane == 0) part[wave] = -10.0f * dot + logf(ps);
    __syncthreads();
    if (tid == 0)
        atomicAdd(out, (part[0] + part[1] + part[2] + part[3]) * (1.0f / N2));
}

extern "C" void kernel_launch(void* const* d_in, const int* in_sizes, int n_in,
                              void* d_out, int out_size, void* d_ws, size_t ws_size,
                              hipStream_t stream)
{
    const float* z1 = (const float*)d_in[0];
    const float* z2 = (const float*)d_in[1];
    float* out      = (float*)d_out;
    unsigned char* U = (unsigned char*)d_ws;
    float* partials  = (float*)((char*)d_ws + U_BYTES);
    float* posdot    = (float*)((char*)d_ws + U_BYTES + PART_BYTES);
    const bool has_pd = ws_size >= U_BYTES + PART_BYTES + PD_BYTES;

    prep_kernel<<<N2 / 4, 256, 0, stream>>>(z1, z2, U, out);
    gram_kernel<<<NTRI, 256, 0, stream>>>(U, partials, has_pd ? posdot : nullptr);
    if (has_pd)
        finalize_fast<<<N2 / 256, 256, 0, stream>>>(partials, posdot, out);
    else
        finalize_slow<<<N2 / 4, 256, 0, stream>>>(U, partials, out);
}